// Round 14
// baseline (364.036 us; speedup 1.0000x reference)
//
#include <hip/hip_runtime.h>
#include <cstdint>
#include <cstddef>

#define T_TOK 64
#define K_IN 4096
#define N_OUT 14336
#define NP 14464                     // Wp row stride (elems): 28,928 B = odd*256 -> k-rows rotate HBM channels
#define SPLITK 16
#define KCHUNK 256                   // K per gemm block (4096/16)
#define NSTAGES 8                    // 8 stages x 32 k
#define WCOLS 64                     // cols per wave (4 interleaved 16-col tiles)
#define BCOLS 128                    // cols per block (2 waves)

typedef __attribute__((ext_vector_type(8))) short bf16x8;
typedef __attribute__((ext_vector_type(4))) float f32x4;
typedef __attribute__((ext_vector_type(4))) int i32x4;
typedef __attribute__((ext_vector_type(2))) int i32x2;

static __device__ __forceinline__ unsigned short bf16_rne(float f) {
    unsigned u = __builtin_bit_cast(unsigned, f);
    unsigned r = (u + 0x7fffu + ((u >> 16) & 1u)) >> 16;
    return (unsigned short)r;
}

// Kernel 1: x (fp32) -> bf16 copy in ws + per-token row sums.
__global__ __launch_bounds__(256) void prep_kernel(const float* __restrict__ x,
                                                   unsigned short* __restrict__ xbf,
                                                   float* __restrict__ rowsum) {
    const int row = blockIdx.x;
    const int t = threadIdx.x;
    const float4* x4 = (const float4*)(x + (size_t)row * K_IN);
    float s = 0.f;
#pragma unroll
    for (int i = 0; i < 4; i++) {
        float4 v = x4[i * 256 + t];
        s += v.x + v.y + v.z + v.w;
        ushort4 h;
        h.x = bf16_rne(v.x); h.y = bf16_rne(v.y);
        h.z = bf16_rne(v.z); h.w = bf16_rne(v.w);
        *(ushort4*)(xbf + (size_t)row * K_IN + (size_t)(i * 256 + t) * 4) = h;
    }
#pragma unroll
    for (int off = 32; off > 0; off >>= 1) s += __shfl_down(s, off, 64);
    __shared__ float part[4];
    const int wave = t >> 6, lane = t & 63;
    if (lane == 0) part[wave] = s;
    __syncthreads();
    if (t == 0) rowsum[row] = part[0] + part[1] + part[2] + part[3];
}

// Kernel 2: repack W -> Wp = bf16(W * scale), padded row stride NP.
// PURE LINEAR STREAM: 4 KB contiguous read / 2 KB contiguous write per instr.
// Grid (14, 256) x 256: block (bx,by) handles k-rows by*16..+15, cols bx*1024..+1023.
// (Rounds 4-13: every k-strided reader of W plateaus at ~2.3 TB/s; W row stride
// 57,344 B is degenerate mod HBM channel interleave. This pass reads W the way
// a memcpy does, and gives the GEMM a channel-rotating layout we control.)
__global__ __launch_bounds__(256) void repack_kernel(const int* __restrict__ W,
                                                     const float* __restrict__ scales,
                                                     unsigned short* __restrict__ Wp) {
    const int col = blockIdx.x * 1024 + threadIdx.x * 4;
    const int k0 = blockIdx.y * 16;
    // scale group is constant across the block's 16 k-rows: (k0..k0+15)>>7 == by>>3
    const float4 sc = *(const float4*)(scales + (size_t)(k0 >> 7) * N_OUT + col);
#pragma unroll
    for (int i = 0; i < 16; i++) {
        const int k = k0 + i;
        i32x4 w;
        {
            const i32x4* p = (const i32x4*)(W + (size_t)k * N_OUT + col);
            w = __builtin_nontemporal_load(p);
        }
        ushort4 h;
        h.x = bf16_rne((float)w[0] * sc.x);
        h.y = bf16_rne((float)w[1] * sc.y);
        h.z = bf16_rne((float)w[2] * sc.z);
        h.w = bf16_rne((float)w[3] * sc.w);
        *(ushort4*)(Wp + (size_t)k * NP + col) = h;
    }
}

// ---- manual-pipeline primitives: inline-asm dwordx2 loads + vmcnt waits.
#define LOAD_B2(dst, p) \
    asm volatile("global_load_dwordx2 %0, %1, off" : "=v"(dst) : "v"(p))

#define WAIT_B2(cnt, B) \
    asm volatile("s_waitcnt vmcnt(" #cnt ")" \
        : "+v"((B)[0]), "+v"((B)[1]), "+v"((B)[2]), "+v"((B)[3]), \
          "+v"((B)[4]), "+v"((B)[5]), "+v"((B)[6]), "+v"((B)[7]))

#define ISSUE_B2(S, B) \
    { \
        LOAD_B2((B)[0], wlane + (size_t)((S) * 32 + 0) * NP); \
        LOAD_B2((B)[1], wlane + (size_t)((S) * 32 + 1) * NP); \
        LOAD_B2((B)[2], wlane + (size_t)((S) * 32 + 2) * NP); \
        LOAD_B2((B)[3], wlane + (size_t)((S) * 32 + 3) * NP); \
        LOAD_B2((B)[4], wlane + (size_t)((S) * 32 + 4) * NP); \
        LOAD_B2((B)[5], wlane + (size_t)((S) * 32 + 5) * NP); \
        LOAD_B2((B)[6], wlane + (size_t)((S) * 32 + 6) * NP); \
        LOAD_B2((B)[7], wlane + (size_t)((S) * 32 + 7) * NP); \
    }

// Kernel 3: split-K bf16 GEMM on Wp (scales pre-applied by repack).
// Grid (112, 16) x 128 thr (2 waves). Wave owns 64 cols as 4 column-interleaved
// MFMA tiles; lane (q,r) loads Wp[k][4r..4r+3] as one dwordx2 (4 bf16).
// Depth-2 asm pipeline, vmcnt(8)/(0). A (64x256 bf16, 32 KB) in LDS, one barrier.
// Epilogue: float4 partial stores (no atomics); reduce_kernel finishes.
__global__ __launch_bounds__(128, 2) void gemm_kernel(const unsigned short* __restrict__ xbf,
                                                      const unsigned short* __restrict__ Wp,
                                                      float* __restrict__ partials) {
    __shared__ char Alds[32768];

    const int tid = threadIdx.x;
    const int wave = tid >> 6;          // 0..1
    const int lane = tid & 63;
    const int q = lane >> 4;            // quad: k-offset q*8 in frags
    const int r = lane & 15;            // tile col index / token row
    const int cb = blockIdx.x;
    const int kbase = blockIdx.y * KCHUNK;
    const int mycol = cb * BCOLS + wave * WCOLS + 4 * r;

    // ---- stage A once: 64 rows x 512 B, 16-B chunk cc stored at cc^(row&7)
#pragma unroll
    for (int half = 0; half < 2; half++) {
        i32x4 av[8];
#pragma unroll
        for (int i = 0; i < 8; i++) {
            const int chunk = (half * 8 + i) * 128 + tid;   // 2048 chunks of 16 B
            const int row = chunk >> 5;
            const int cc = chunk & 31;
            av[i] = *(const i32x4*)(xbf + (size_t)row * K_IN + kbase + cc * 8);
        }
#pragma unroll
        for (int i = 0; i < 8; i++) {
            const int chunk = (half * 8 + i) * 128 + tid;
            const int row = chunk >> 5;
            const int cc = chunk & 31;
            *(i32x4*)(Alds + row * 512 + (cc ^ (row & 7)) * 16) = av[i];
        }
    }
    __syncthreads();   // ONLY barrier: A visible; all compiler vmem drained

    const unsigned short* wlane = Wp + (size_t)(kbase + q * 8) * NP + mycol;

    f32x4 acc[4][4];   // [col-tile c][M-tile mt]
#pragma unroll
    for (int c = 0; c < 4; c++)
#pragma unroll
        for (int mt = 0; mt < 4; mt++) acc[c][mt] = f32x4{0.f, 0.f, 0.f, 0.f};

    auto consume = [&](int s, i32x2 (&B)[8]) {
        bf16x8 bf[4];
#pragma unroll
        for (int c = 0; c < 4; c++)
#pragma unroll
            for (int j = 0; j < 8; j++) {
                const int v = B[j][c >> 1];
                bf[c][j] = (short)((c & 1) ? (v >> 16) : (v & 0xffff));
            }
#pragma unroll
        for (int mt = 0; mt < 4; mt++) {
            bf16x8 af = *(const bf16x8*)(Alds + (r + mt * 16) * 512 + (((s * 4 + q) ^ (r & 7)) << 4));
#pragma unroll
            for (int c = 0; c < 4; c++)
                acc[c][mt] = __builtin_amdgcn_mfma_f32_16x16x32_bf16(af, bf[c], acc[c][mt], 0, 0, 0);
        }
    };

    i32x2 b0[8], b1[8];
    ISSUE_B2(0, b0); ISSUE_B2(1, b1);
    WAIT_B2(8, b0); consume(0, b0); ISSUE_B2(2, b0);
    WAIT_B2(8, b1); consume(1, b1); ISSUE_B2(3, b1);
    WAIT_B2(8, b0); consume(2, b0); ISSUE_B2(4, b0);
    WAIT_B2(8, b1); consume(3, b1); ISSUE_B2(5, b1);
    WAIT_B2(8, b0); consume(4, b0); ISSUE_B2(6, b0);
    WAIT_B2(8, b1); consume(5, b1); ISSUE_B2(7, b1);
    WAIT_B2(8, b0); consume(6, b0);
    WAIT_B2(0, b1); consume(7, b1);

    // epilogue: float4 partial stores. D tile c: row t = mt*16+q*4+i,
    // actual col = mycol + c -> the 4 tiles pack into one float4 per lane.
    float* pb = partials + (size_t)blockIdx.y * T_TOK * N_OUT + mycol;
#pragma unroll
    for (int mt = 0; mt < 4; mt++) {
#pragma unroll
        for (int i = 0; i < 4; i++) {
            const int t = mt * 16 + q * 4 + i;
            float4 v;
            v.x = acc[0][mt][i]; v.y = acc[1][mt][i];
            v.z = acc[2][mt][i]; v.w = acc[3][mt][i];
            *(float4*)(pb + (size_t)t * N_OUT) = v;
        }
    }
}

// Kernel 4: out[t][col] = bias + rowsum[t]*u + sum_sk partials[sk][t][col].
__global__ __launch_bounds__(256) void reduce_kernel(const float* __restrict__ partials,
                                                     const float* __restrict__ rowsum,
                                                     const float* __restrict__ u,
                                                     const float* __restrict__ bias,
                                                     float* __restrict__ out) {
    const int t = blockIdx.y;
    const int n4 = blockIdx.x * 256 + threadIdx.x;      // float4 index within row
    const float rs = rowsum[t];
    float4 b = ((const float4*)bias)[n4];
    float4 uu = ((const float4*)u)[n4];
    float4 s;
    s.x = b.x + rs * uu.x; s.y = b.y + rs * uu.y;
    s.z = b.z + rs * uu.z; s.w = b.w + rs * uu.w;
    const float4* p = (const float4*)(partials + (size_t)t * N_OUT) + n4;
#pragma unroll
    for (int sk = 0; sk < SPLITK; sk++) {
        float4 v = p[(size_t)sk * (T_TOK * N_OUT / 4)];
        s.x += v.x; s.y += v.y; s.z += v.z; s.w += v.w;
    }
    ((float4*)(out + (size_t)t * N_OUT))[n4] = s;
}

extern "C" void kernel_launch(void* const* d_in, const int* in_sizes, int n_in,
                              void* d_out, int out_size, void* d_ws, size_t ws_size,
                              hipStream_t stream) {
    const float* x      = (const float*)d_in[0];
    const int*   W      = (const int*)d_in[1];
    const float* scales = (const float*)d_in[2];
    const float* u      = (const float*)d_in[3];
    const float* bias   = (const float*)d_in[4];
    float* out = (float*)d_out;

    unsigned short* xbf = (unsigned short*)d_ws;                    // 512 KB @ 0
    float* rowsum   = (float*)((char*)d_ws + (512 << 10));          // 256 B
    float* partials = (float*)((char*)d_ws + (1 << 20));            // 58.7 MB @ 1 MB
    unsigned short* Wp = (unsigned short*)((char*)d_ws + ((size_t)64 << 20)); // 118.5 MB @ 64 MB

    prep_kernel<<<T_TOK, 256, 0, stream>>>(x, xbf, rowsum);
    repack_kernel<<<dim3(N_OUT / 1024, K_IN / 16), 256, 0, stream>>>(W, scales, Wp);
    gemm_kernel<<<dim3(N_OUT / BCOLS, SPLITK), 128, 0, stream>>>(xbf, Wp, partials);
    reduce_kernel<<<dim3(N_OUT / 4 / 256, T_TOK), 256, 0, stream>>>(partials, rowsum, u, bias, out);
}